// Round 15
// baseline (4112.822 us; speedup 1.0000x reference)
//
#include <hip/hip_runtime.h>
#include <hip/hip_bf16.h>

// LSTM forward, T=512 B=128 D=1024 H=1024, fp32 in/out, bf16 MFMA compute.
//
// Round 15: sound-transport rebuild. R11-R14 post-mortem: every failure
// shared one variable — cached-h consumer loads under the XCD remap; the
// plain-cached path is placement-sensitive and not provably fresh. This
// kernel uses ONLY the proven sc1 transport (R8/R9, placement-independent):
//  - h publish sc1 -> syncthreads(drain) -> block flag sc1 (R9 protocol)
//  - NEW per-wave poll+fill: wave w polls its 4 producers {4w..4w+3} then
//    sc1-fills its k8 range [16w,16w+16) into LDS (staged, 1 RTT). Producer
//    jitter stalls one wave, not the whole block; one barrier removed
//    (2/step instead of 3). Post-spin IR fence + sched_barrier pins the
//    load-after-flag order (loads are sc1 -> no cache-freshness concern).
//  - gx ring as bf16 u64 (R10-validated, sc1): halves the biggest write.
//  - X engine byte-identical to R10. Mapping g=bid>>5 (R9/R10 spread).

#define NT 512
#define NB 128
#define ND 1024
#define NH 1024
#define FSTR 16                 // u32 per flag slot (64 B)
#define GUARD_STEP (1 << 17)
#define GUARD_BOOT (1 << 22)

// post-spin fence: forbid hoisting the dependent loads above the spin exit
#define FENCE_ACQ() do { asm volatile("" ::: "memory"); \
                         __builtin_amdgcn_sched_barrier(0); } while (0)

typedef __attribute__((ext_vector_type(8))) __bf16 bf16x8;
typedef __attribute__((ext_vector_type(4))) float  f32x4;
typedef __attribute__((ext_vector_type(2))) unsigned long long ullx2;
typedef unsigned long long u64;

__device__ __forceinline__ float sigm(float x) { return 1.0f / (1.0f + __expf(-x)); }
__device__ __forceinline__ float tanh_(float x) {
    x = fminf(15.0f, fmaxf(-15.0f, x));
    float e = __expf(-2.0f * x);
    return (1.0f - e) / (1.0f + e);
}
__device__ __forceinline__ bf16x8 cvt8v(float4 f0, float4 f1) {
    bf16x8 v;
    v[0] = (__bf16)f0.x; v[1] = (__bf16)f0.y; v[2] = (__bf16)f0.z; v[3] = (__bf16)f0.w;
    v[4] = (__bf16)f1.x; v[5] = (__bf16)f1.y; v[6] = (__bf16)f1.z; v[7] = (__bf16)f1.w;
    return v;
}
__device__ __forceinline__ bf16x8 cvt8(const float* p) {
    return cvt8v(*(const float4*)p, *(const float4*)(p + 4));
}
__device__ __forceinline__ u64 ald(const u64* p) {
    return __hip_atomic_load(p, __ATOMIC_RELAXED, __HIP_MEMORY_SCOPE_AGENT);
}
__device__ __forceinline__ void ast(u64* p, u64 v) {
    __hip_atomic_store(p, v, __ATOMIC_RELAXED, __HIP_MEMORY_SCOPE_AGENT);
}
__device__ __forceinline__ unsigned aldu(const unsigned* p) {
    return __hip_atomic_load(p, __ATOMIC_RELAXED, __HIP_MEMORY_SCOPE_AGENT);
}
__device__ __forceinline__ void astu(unsigned* p, unsigned v) {
    __hip_atomic_store(p, v, __ATOMIC_RELAXED, __HIP_MEMORY_SCOPE_AGENT);
}
__device__ __forceinline__ float b2f(unsigned bits16) {
    return __builtin_bit_cast(float, bits16 << 16);
}
__device__ __forceinline__ u64 pack4(f32x4 v) {
    const unsigned short h0 = __builtin_bit_cast(unsigned short, (__bf16)v[0]);
    const unsigned short h1 = __builtin_bit_cast(unsigned short, (__bf16)v[1]);
    const unsigned short h2 = __builtin_bit_cast(unsigned short, (__bf16)v[2]);
    const unsigned short h3 = __builtin_bit_cast(unsigned short, (__bf16)v[3]);
    return (u64)h0 | ((u64)h1 << 16) | ((u64)h2 << 32) | ((u64)h3 << 48);
}

__global__ void __launch_bounds__(512, 2)
lstm_main(const float* __restrict__ x, const float* __restrict__ w_ih,
          const float* __restrict__ b_ih, const float* __restrict__ w_hh,
          const float* __restrict__ b_hh, float* __restrict__ out,
          u64* __restrict__ gxr,          // [4 slot][32 xblk][128 wcol][32 u64] bf16x4
          unsigned* __restrict__ hbuf,    // [4 grp][2 pp][128 k8][32 row][8 bf16]
          unsigned* __restrict__ l3f,     // [4 grp][32 blk] epoch (L3)
          unsigned* __restrict__ xfl)     // [32 xblk][4 slot] epoch (L3)
{
    __shared__ uint4 ldsA[4096];          // 64 KB: [k8 128][row 32] bf16x8
    __shared__ float scr[8][32][17];      // per-wave gate exchange

    const int tid  = threadIdx.x;
    const int lane = tid & 63;
    const int wid  = tid >> 6;
    const int bid  = blockIdx.x;
    const int c = lane & 15, kslot = lane >> 4;

    if (bid < 128) {
        // ================= H engine (recurrence) =================
        const int g = bid >> 5, blk = bid & 31;   // R9/R10 spread mapping

        bf16x8 wreg[32];
        {
            const size_t grow = (size_t)(c >> 2) * NH + blk * 32 + 4 * wid + (c & 3);
            const float* wp = w_hh + grow * NH + kslot * 8;
            #pragma unroll
            for (int kk = 0; kk < 32; ++kk) wreg[kk] = cvt8(wp + kk * 32);
        }
        const int row_l = lane >> 1;
        const int jjo   = (lane & 1) * 2;
        const int j0    = blk * 32 + 4 * wid + jjo;
        float bias[4][2];
        #pragma unroll
        for (int gg = 0; gg < 4; ++gg)
            #pragma unroll
            for (int u = 0; u < 2; ++u)
                bias[gg][u] = b_ih[gg * NH + j0 + u] + b_hh[gg * NH + j0 + u];
        float cst[2] = {0.f, 0.f};

        unsigned* postl3 = l3f + ((size_t)g * 32 + blk) * FSTR;

        f32x4 gxc0, gxc1;
        #define GXLOAD(sl) do {                                                      \
            const u64* gp_ = gxr + (((size_t)(sl)) * 32 + blk) * 4096                \
                             + (size_t)(wid * 16 + c) * 32 + 8 * g;                  \
            const u64 q0_ = ald(gp_ + kslot);                                        \
            const u64 q1_ = ald(gp_ + 4 + kslot);                                    \
            gxc0[0] = b2f((unsigned)q0_ & 0xffffu);                                  \
            gxc0[1] = b2f(((unsigned)q0_) >> 16);                                    \
            gxc0[2] = b2f((unsigned)(q0_ >> 32) & 0xffffu);                          \
            gxc0[3] = b2f((unsigned)(q0_ >> 48));                                    \
            gxc1[0] = b2f((unsigned)q1_ & 0xffffu);                                  \
            gxc1[1] = b2f(((unsigned)q1_) >> 16);                                    \
            gxc1[2] = b2f((unsigned)(q1_ >> 32) & 0xffffu);                          \
            gxc1[3] = b2f((unsigned)(q1_ >> 48));                                    \
        } while (0)

        {   // prologue: wait for gx[0]
            const unsigned* xfp0 = xfl + ((size_t)blk * 4 + 0) * FSTR;
            int gu = 0;
            while (aldu(xfp0) < 1u) {
                __builtin_amdgcn_s_sleep(8);
                if (++gu > GUARD_BOOT) break;
            }
            FENCE_ACQ();
            GXLOAD(0);
        }

        for (int t = 0; t < NT; ++t) {
            if (t) {
                // ---- per-wave poll: my 4 producers {4w..4w+3} posted >= t ----
                {
                    int gu = 0;
                    for (;;) {
                        unsigned v = 0xffffffffu;
                        if (lane < 4)
                            v = aldu(l3f + ((size_t)g * 32 + 4 * wid + lane) * FSTR);
                        if (__all(v >= (unsigned)t)) break;
                        __builtin_amdgcn_s_sleep(1);
                        if (++gu > GUARD_STEP) break;
                    }
                }
                FENCE_ACQ();   // sc1 fills below must not precede the flag check

                // ---- per-wave A-fill: k8 in [16w,16w+16), staged sc1 (1 RTT) ----
                const u64* s8 = (const u64*)(const void*)
                    (hbuf + ((size_t)g * 2 + ((t + 1) & 1)) * 16384);
                u64 st[16];
                #pragma unroll
                for (int i = 0; i < 8; ++i) {
                    const int idx = i * 64 + lane;           // 0..511 in-wave
                    const int k8  = 16 * wid + (idx >> 5);
                    const int row = idx & 31;
                    const size_t q = (size_t)(k8 * 32 + row) * 2;
                    st[2 * i]     = ald(s8 + q);
                    st[2 * i + 1] = ald(s8 + q + 1);
                }
                #pragma unroll
                for (int i = 0; i < 8; ++i) {
                    const int idx = i * 64 + lane;
                    const int k8  = 16 * wid + (idx >> 5);
                    const int row = idx & 31;
                    ullx2 tq; tq[0] = st[2 * i]; tq[1] = st[2 * i + 1];
                    ldsA[k8 * 32 + row] = __builtin_bit_cast(uint4, tq);
                }
            }
            // early epoch sample for gx[t+1]
            const unsigned* xfp = xfl + ((size_t)blk * 4 + ((t + 1) & 3)) * FSTR;
            unsigned xfNext = 0xffffffffu;
            if (t + 1 < NT) xfNext = aldu(xfp);
            __syncthreads();   // all waves' fills visible to all (pre-GEMM)

            f32x4 acc0, acc1;
            if (t) {
                f32x4 a0a = gxc0, a1a = gxc1;
                f32x4 a0b = {0,0,0,0}, a1b = {0,0,0,0};
                #pragma unroll
                for (int kk = 0; kk < 32; ++kk) {
                    const bf16x8 a0 = __builtin_bit_cast(bf16x8, ldsA[(kk*4 + kslot)*32 + c]);
                    const bf16x8 a1 = __builtin_bit_cast(bf16x8, ldsA[(kk*4 + kslot)*32 + 16 + c]);
                    if (kk & 1) {
                        a0b = __builtin_amdgcn_mfma_f32_16x16x32_bf16(a0, wreg[kk], a0b, 0,0,0);
                        a1b = __builtin_amdgcn_mfma_f32_16x16x32_bf16(a1, wreg[kk], a1b, 0,0,0);
                    } else {
                        a0a = __builtin_amdgcn_mfma_f32_16x16x32_bf16(a0, wreg[kk], a0a, 0,0,0);
                        a1a = __builtin_amdgcn_mfma_f32_16x16x32_bf16(a1, wreg[kk], a1a, 0,0,0);
                    }
                }
                acc0 = a0a + a0b; acc1 = a1a + a1b;
            } else {
                acc0 = gxc0; acc1 = gxc1;
            }

            // intra-wave gate exchange (C-layout: col=lane&15, row=(lane>>4)*4+r)
            #pragma unroll
            for (int r = 0; r < 4; ++r) {
                scr[wid][kslot * 4 + r][c]      = acc0[r];
                scr[wid][16 + kslot * 4 + r][c] = acc1[r];
            }
            // cell update: lane finishes cells (row_l, j0) and (row_l, j0+1)
            float hv[2];
            #pragma unroll
            for (int u = 0; u < 2; ++u) {
                const float iv = sigm (scr[wid][row_l][ 0 + jjo + u] + bias[0][u]);
                const float fv = sigm (scr[wid][row_l][ 4 + jjo + u] + bias[1][u]);
                const float gv = tanh_(scr[wid][row_l][ 8 + jjo + u] + bias[2][u]);
                const float ov = sigm (scr[wid][row_l][12 + jjo + u] + bias[3][u]);
                const float cc = fv * cst[u] + iv * gv;
                cst[u] = cc;
                hv[u] = ov * tanh_(cc);
            }

            // publish h_t (tiled bf16, sc1) -> drain -> flag
            {
                const unsigned short u0 = __builtin_bit_cast(unsigned short, (__bf16)hv[0]);
                const unsigned short u1 = __builtin_bit_cast(unsigned short, (__bf16)hv[1]);
                const unsigned pack = (unsigned)u0 | ((unsigned)u1 << 16);
                const size_t hidx = ((size_t)g * 2 + (t & 1)) * 16384
                                  + ((size_t)(j0 >> 3) * 32 + row_l) * 4 + ((j0 & 7) >> 1);
                astu(&hbuf[hidx], pack);
            }
            __syncthreads();   // vmcnt(0): h stores at L3 before the flag
            if (tid == 0) astu(postl3, (unsigned)(t + 1));

            // off-critical-path out stores (after flag post)
            {
                float2 o; o.x = hv[0]; o.y = hv[1];
                *(float2*)&out[((size_t)t * NB + 32 * g + row_l) * NH + j0] = o;
                if (t == NT - 1)
                    *(float2*)&out[(size_t)NT * NB * NH + ((size_t)32 * g + row_l) * NH + j0] = o;
            }
            // prefetch gx[t+1]
            if (t + 1 < NT) {
                int gu = 0;
                while (xfNext < (unsigned)(t + 2)) {
                    __builtin_amdgcn_s_sleep(1);
                    xfNext = aldu(xfp);
                    if (++gu > GUARD_STEP) break;
                }
                FENCE_ACQ();
                GXLOAD((t + 1) & 3);
            }
        }
        {   // c_n
            float2 cn; cn.x = cst[0]; cn.y = cst[1];
            *(float2*)&out[(size_t)NT * NB * NH + (size_t)NB * NH
                           + ((size_t)32 * g + row_l) * NH + j0] = cn;
        }
    } else {
        // ================= X engine (gx producer, runs ahead) =================
        const int e = (bid - 128) >> 5, r = bid & 31;

        bf16x8 wreg[32];
        {
            const size_t grow = (size_t)(c >> 2) * NH + r * 32 + 4 * wid + (c & 3);
            const float* wp = w_ih + grow * ND + kslot * 8;
            #pragma unroll
            for (int kk = 0; kk < 32; ++kk) wreg[kk] = cvt8(wp + kk * 32);
        }
        const int xrow = tid >> 4, seg = tid & 15;

        for (int tt = e; tt < NT; tt += 4) {
            if (tt >= 4) {
                // throttle: all 4 consumer groups must have finished step tt-4
                const unsigned* hp = l3f + ((size_t)(lane & 3) * 32 + r) * FSTR;
                int gu = 0;
                while (aldu(hp) < (unsigned)(tt - 3)) {
                    __builtin_amdgcn_s_sleep(4);
                    if (++gu > GUARD_STEP) break;
                }
            }
            __syncthreads();

            f32x4 xa0={0,0,0,0}, xa1={0,0,0,0}, xa2={0,0,0,0}, xa3={0,0,0,0};
            f32x4 xa4={0,0,0,0}, xa5={0,0,0,0}, xa6={0,0,0,0}, xa7={0,0,0,0};

            // staged x-chunk: issue all 16 float4 loads, then convert+write
            #define XCHUNK(m, A, B) {                                                \
                const float* xs = x + ((size_t)tt * NB + 32 * (m) + xrow) * ND       \
                                    + seg * 64;                                      \
                float4 xf[16];                                                       \
                _Pragma("unroll")                                                    \
                for (int i2 = 0; i2 < 8; ++i2) {                                     \
                    xf[2 * i2]     = *(const float4*)(xs + i2 * 8);                  \
                    xf[2 * i2 + 1] = *(const float4*)(xs + i2 * 8 + 4);              \
                }                                                                    \
                _Pragma("unroll")                                                    \
                for (int i2 = 0; i2 < 8; ++i2)                                       \
                    ldsA[(seg * 8 + i2) * 32 + xrow] =                               \
                        __builtin_bit_cast(uint4, cvt8v(xf[2*i2], xf[2*i2+1]));      \
                __syncthreads();                                                     \
                _Pragma("unroll")                                                    \
                for (int kk = 0; kk < 32; ++kk) {                                    \
                    const bf16x8 a0 = __builtin_bit_cast(bf16x8,                     \
                        ldsA[(kk*4 + kslot)*32 + c]);                                \
                    const bf16x8 a1 = __builtin_bit_cast(bf16x8,                     \
                        ldsA[(kk*4 + kslot)*32 + 16 + c]);                           \
                    A = __builtin_amdgcn_mfma_f32_16x16x32_bf16(a0, wreg[kk], A, 0,0,0);\
                    B = __builtin_amdgcn_mfma_f32_16x16x32_bf16(a1, wreg[kk], B, 0,0,0);\
                }                                                                    \
                __syncthreads(); }

            XCHUNK(0, xa0, xa1)
            XCHUNK(1, xa2, xa3)
            XCHUNK(2, xa4, xa5)
            XCHUNK(3, xa6, xa7)

            {   // store gx[tt] slot as bf16 (sc1 -> L3): u64 = 4 consecutive rows
                u64* gp = gxr + (((size_t)(tt & 3)) * 32 + r) * 4096
                          + (size_t)(wid * 16 + c) * 32;
                ast(gp + kslot,      pack4(xa0));
                ast(gp + 4 + kslot,  pack4(xa1));
                ast(gp + 8 + kslot,  pack4(xa2));
                ast(gp + 12 + kslot, pack4(xa3));
                ast(gp + 16 + kslot, pack4(xa4));
                ast(gp + 20 + kslot, pack4(xa5));
                ast(gp + 24 + kslot, pack4(xa6));
                ast(gp + 28 + kslot, pack4(xa7));
            }
            __syncthreads();   // drain vmcnt: slot data at L3 before the flag
            if (tid == 0)
                astu(xfl + ((size_t)r * 4 + (tt & 3)) * FSTR, (unsigned)(tt + 1));
        }
    }
}

extern "C" void kernel_launch(void* const* d_in, const int* in_sizes, int n_in,
                              void* d_out, int out_size, void* d_ws, size_t ws_size,
                              hipStream_t stream)
{
    const float* x    = (const float*)d_in[0];
    const float* w_ih = (const float*)d_in[1];
    const float* b_ih = (const float*)d_in[2];
    const float* w_hh = (const float*)d_in[3];
    const float* b_hh = (const float*)d_in[4];
    float* out = (float*)d_out;

    const size_t gx_bytes = (size_t)4 * 32 * 4096 * sizeof(u64);      // 4 MB (bf16)
    const size_t hb_bytes = (size_t)4 * 2 * 16384 * sizeof(unsigned); // 512 KB
    const size_t fl_bytes = (size_t)128 * FSTR * sizeof(unsigned);    // 8 KB each
    const size_t total    = gx_bytes + hb_bytes + 2 * fl_bytes;
    if (ws_size < total) return;

    char* p = (char*)d_ws;
    u64*      gxr  = (u64*)p;        p += gx_bytes;
    unsigned* hbuf = (unsigned*)p;   p += hb_bytes;
    unsigned* l3f  = (unsigned*)p;   p += fl_bytes;
    unsigned* xfl  = (unsigned*)p;

    // zero everything each call: epochs restart at 0; no stale/poison data
    hipMemsetAsync(d_ws, 0, total, stream);

    void* args[] = { (void*)&x, (void*)&w_ih, (void*)&b_ih, (void*)&w_hh,
                     (void*)&b_hh, (void*)&out, (void*)&gxr, (void*)&hbuf,
                     (void*)&l3f, (void*)&xfl };
    hipError_t err = hipLaunchCooperativeKernel((const void*)lstm_main,
                                                dim3(256), dim3(512),
                                                args, 0, stream);
    if (err != hipSuccess) {
        // LDS (~83 KB) forces 1 block/CU; 256 blocks co-reside on 256 CUs
        lstm_main<<<dim3(256), dim3(512), 0, stream>>>(x, w_ih, b_ih, w_hh, b_hh,
                                                       out, gxr, hbuf, l3f, xfl);
    }
}